// Round 4
// baseline (1594.641 us; speedup 1.0000x reference)
//
#include <hip/hip_runtime.h>
#include <math.h>

namespace {
constexpr int kN = 16384;
constexpr int kD = 2048;
constexpr int kH = 4096;
constexpr int kE = 64;
constexpr int kShared = 8;

// d_out layout (floats), reference return order
constexpr int OFF_GW = 0;                       // global_weights: N x 8
constexpr int OFF_LW = kN * kShared;            // local_weights:  N x 2
constexpr int OFF_LI = OFF_LW + kN * 2;         // local_indices:  N x 2 (as float)
constexpr int OFF_W  = OFF_LI + kN * 2;         // weights: N x 64 -- logit accumulator in atomic mode

constexpr int HSPLIT = 4;
constexpr int CHUNKS = 8;        // 8 x 128 = 1024 H-cols per block
constexpr int GS_STRIDE = 68;    // 64 rows + 4 pad

// workspace layout (f16 elements from base)
constexpr size_t XH_OFF  = 0;
constexpr size_t XL_OFF  = (size_t)kN * kD;
constexpr size_t W1TH_OFF = XL_OFF + (size_t)kN * kD;
constexpr size_t W1TL_OFF = W1TH_OFF + (size_t)kH * kD;
constexpr size_t WS_BASE = (W1TL_OFF + (size_t)kH * kD) * 2;          // bytes: 167,772,160
constexpr size_t PART_FLOAT_OFF = WS_BASE / 4;                         // float index of partials
constexpr size_t WS_FULL = WS_BASE + (size_t)HSPLIT * kN * kE * 4;     // + 16.8 MB partials

// compile-time plane deltas (f16 elements)
constexpr unsigned DXL = (unsigned)XL_OFF;                  // Ah -> Al
constexpr unsigned DWL = (unsigned)(W1TL_OFF - W1TH_OFF);   // Bh -> Bl
constexpr unsigned D64 = 64u * kD;                          // B rows +64
}

typedef _Float16 half8  __attribute__((ext_vector_type(8)));
typedef _Float16 half4t __attribute__((ext_vector_type(4)));
typedef float    f32x16 __attribute__((ext_vector_type(16)));

__device__ __forceinline__ void async16(const _Float16* g, _Float16* l) {
    __builtin_amdgcn_global_load_lds(
        (const __attribute__((address_space(1))) void*)g,
        (__attribute__((address_space(3))) void*)l, 16, 0, 0);
}

// ---------------------------------------------------------------------------
// Pre-pass 1: x (fp32) -> xh, xl (f16 planes; xl pre-scaled by 2048)
// ---------------------------------------------------------------------------
__global__ __launch_bounds__(256)
void convert_x(const float* __restrict__ x, _Float16* __restrict__ xh,
               _Float16* __restrict__ xl)
{
    const size_t i = ((size_t)blockIdx.x * 256 + threadIdx.x) * 4;
    const float4 v = *reinterpret_cast<const float4*>(x + i);
    half4t h, l;
    const float vs[4] = {v.x, v.y, v.z, v.w};
    #pragma unroll
    for (int j = 0; j < 4; ++j) {
        const _Float16 hj = (_Float16)vs[j];
        h[j] = hj;
        l[j] = (_Float16)((vs[j] - (float)hj) * 2048.0f);
    }
    *reinterpret_cast<half4t*>(xh + i) = h;
    *reinterpret_cast<half4t*>(xl + i) = l;
}

// ---------------------------------------------------------------------------
// Pre-pass 2: W1 [D][H] fp32 -> W1^T hi/lo planes [H][D] f16 (lo scaled 2048)
// ---------------------------------------------------------------------------
__global__ __launch_bounds__(256)
void convert_w1t(const float* __restrict__ W1, _Float16* __restrict__ th,
                 _Float16* __restrict__ tl)
{
    __shared__ float T[64][65];
    const int bk = blockIdx.x & 31;
    const int bn = blockIdx.x >> 5;
    const int k0 = bk * 64, n0 = bn * 64;
    const int t = threadIdx.x;
    const int c4 = (t & 15) * 4, r = t >> 4;

    #pragma unroll
    for (int i = 0; i < 4; ++i) {
        const int kk = r + 16 * i;
        const float4 v = *reinterpret_cast<const float4*>(
            W1 + (size_t)(k0 + kk) * kH + n0 + c4);
        T[kk][c4 + 0] = v.x; T[kk][c4 + 1] = v.y;
        T[kk][c4 + 2] = v.z; T[kk][c4 + 3] = v.w;
    }
    __syncthreads();
    #pragma unroll
    for (int i = 0; i < 4; ++i) {
        const int nn = r + 16 * i;
        half4t h, l;
        #pragma unroll
        for (int j = 0; j < 4; ++j) {
            const float vv = T[c4 + j][nn];
            const _Float16 hj = (_Float16)vv;
            h[j] = hj;
            l[j] = (_Float16)((vv - (float)hj) * 2048.0f);
        }
        *reinterpret_cast<half4t*>(th + (size_t)(n0 + nn) * kD + k0 + c4) = h;
        *reinterpret_cast<half4t*>(tl + (size_t)(n0 + nn) * kD + k0 + c4) = l;
    }
}

// ---------------------------------------------------------------------------
// GEMM1 split-f16 3-pass MFMA, fused gelu + GEMM2 partial.
// Block tile: 64 rows x 128 H-cols, 8 chunks (1024 H per block / hSplit).
// grid = 1024 (256 rowblocks x 4 hSplits), block = 256 (4 waves).
// Wave tile 32x64 -> 64 acc floats -> ~120 VGPR -> 4 blocks/CU (16 waves)
// for 4-way barrier-stall overlap (was 2-way at 22% occupancy).
// Staging source-permuted (chunk q at phys q ^ (r&3) ^ ((r>>2)&3)): 0 conflicts.
// ---------------------------------------------------------------------------
__global__ __launch_bounds__(256, 4)
void gemm1_mfma(const _Float16* __restrict__ xh, const float* __restrict__ b1,
                const float* __restrict__ W2, float* __restrict__ dst,
                int atomicMode)
{
    // union: staging 24 KB (Ah 4K | Al 4K | Bh 8K | Bl 8K) / gS 64x68 f32 (17.4 KB)
    __shared__ __align__(16) float smem[6144];
    _Float16* lds = (_Float16*)smem;
    float* gS = smem;

    const int t = threadIdx.x;
    const int lane = t & 63;
    const int w = t >> 6;
    const int bx = blockIdx.x;
    const int hSplit = bx & 3;          // per-XCD W1-slice locality
    const int rowBase = (bx >> 2) * 64;

    const int mw = (w & 1) * 32;        // wave rows within 64
    const int nw = (w >> 1) * 64;       // wave cols within 128

    // --- staging source offsets (f16 elements rel. xh), source-permuted.
    // Slot s=t: row = t>>2, logical chunk pq = t&3, phys q = pq ^ swz(row).
    {
    }
    const int srow = t >> 2;
    const int sq = (t & 3) ^ (srow & 3) ^ ((srow >> 2) & 3);
    const unsigned gofsA0 = (unsigned)XH_OFF + (unsigned)(rowBase + srow) * kD + sq * 8;
    const unsigned gofsB0 = (unsigned)W1TH_OFF + (unsigned)srow * kD + sq * 8;

    // --- frag LDS offsets (f16 elems), swizzle-aware; ks toggles via ^16,
    // nt via +1024, lo-planes via +2048 (A) / +4096 (B) element offsets.
    const int ar = mw + (lane & 31);
    const int aOff = ar * 32 + ((((lane >> 5)) ^ (ar & 3) ^ ((ar >> 2) & 3)) * 8);
    const int br = nw + (lane & 31);
    const int bOff = br * 32 + ((((lane >> 5)) ^ (br & 3) ^ ((br >> 2) & 3)) * 8);

    // --- GEMM2 accumulators: 2 rows x 8 experts per thread
    const int g_r0 = (t >> 3) * 2;
    const int g_e0 = (t & 7) * 8;
    float lacc[2][8];
    #pragma unroll
    for (int i = 0; i < 2; ++i)
        #pragma unroll
        for (int j = 0; j < 8; ++j) lacc[i][j] = 0.0f;

    for (int chunk = 0; chunk < CHUNKS; ++chunk) {
        const int hBase = hSplit * (CHUNKS * 128) + chunk * 128;
        const unsigned hOff = (unsigned)hBase * kD;

        f32x16 accH[2], accL[2];
        #pragma unroll
        for (int b = 0; b < 2; ++b)
            #pragma unroll
            for (int r = 0; r < 16; ++r) { accH[b][r] = 0.0f; accL[b][r] = 0.0f; }

        for (int kt = 0; kt < kD; kt += 32) {
            __syncthreads();
            async16(xh + gofsA0 + kt,              lds + t * 8);            // Ah
            async16(xh + gofsA0 + DXL + kt,        lds + 2048 + t * 8);     // Al
            async16(xh + gofsB0 + hOff + kt,       lds + 4096 + t * 8);     // Bh r0-63
            async16(xh + gofsB0 + D64 + hOff + kt, lds + 6144 + t * 8);     // Bh r64-127
            async16(xh + gofsB0 + DWL + hOff + kt, lds + 8192 + t * 8);     // Bl r0-63
            async16(xh + gofsB0 + DWL + D64 + hOff + kt, lds + 10240 + t * 8); // Bl r64-127
            __syncthreads();

            #pragma unroll
            for (int ks = 0; ks < 2; ++ks) {
                const int aO = aOff ^ (ks * 16);
                const int bO = bOff ^ (ks * 16);
                const half8 aH  = *reinterpret_cast<const half8*>(lds + aO);
                const half8 aL  = *reinterpret_cast<const half8*>(lds + 2048 + aO);
                const half8 bH0 = *reinterpret_cast<const half8*>(lds + 4096 + bO);
                const half8 bH1 = *reinterpret_cast<const half8*>(lds + 5120 + bO);
                const half8 bL0 = *reinterpret_cast<const half8*>(lds + 8192 + bO);
                const half8 bL1 = *reinterpret_cast<const half8*>(lds + 9216 + bO);
                accH[0] = __builtin_amdgcn_mfma_f32_32x32x16_f16(aH, bH0, accH[0], 0, 0, 0);
                accL[0] = __builtin_amdgcn_mfma_f32_32x32x16_f16(aH, bL0, accL[0], 0, 0, 0);
                accL[0] = __builtin_amdgcn_mfma_f32_32x32x16_f16(aL, bH0, accL[0], 0, 0, 0);
                accH[1] = __builtin_amdgcn_mfma_f32_32x32x16_f16(aH, bH1, accH[1], 0, 0, 0);
                accL[1] = __builtin_amdgcn_mfma_f32_32x32x16_f16(aH, bL1, accL[1], 0, 0, 0);
                accL[1] = __builtin_amdgcn_mfma_f32_32x32x16_f16(aL, bH1, accL[1], 0, 0, 0);
            }
        }

        // --- epilogue: combine + bias + gelu -> gS (g^T 64h x 64r), GEMM2 partial
        const float inv2048 = 1.0f / 2048.0f;
        for (int hf = 0; hf < 2; ++hf) {
            __syncthreads();
            if ((w >> 1) == hf) {           // the 2 waves holding these 64 cols
                #pragma unroll
                for (int nt = 0; nt < 2; ++nt) {
                    const int hl = nt * 32 + (lane & 31);
                    const float bb = b1[hBase + hf * 64 + hl];
                    #pragma unroll
                    for (int rq = 0; rq < 4; ++rq) {
                        float vr[4];
                        #pragma unroll
                        for (int rr = 0; rr < 4; ++rr) {
                            const int r = rq * 4 + rr;
                            const float hv = accH[nt][r] + accL[nt][r] * inv2048 + bb;
                            vr[rr] = 0.5f * hv * (1.0f + erff(hv * 0.70710678118654752f));
                        }
                        const int mrow = mw + 8 * rq + 4 * (lane >> 5);
                        *reinterpret_cast<float4*>(gS + hl * GS_STRIDE + mrow) =
                            make_float4(vr[0], vr[1], vr[2], vr[3]);
                    }
                }
            }
            __syncthreads();
            const float* W2p = W2 + (size_t)(hBase + hf * 64) * kE + g_e0;
            #pragma unroll 4
            for (int h = 0; h < 64; ++h) {
                const float2 gv = *reinterpret_cast<const float2*>(gS + h * GS_STRIDE + g_r0);
                const float4 w0 = *reinterpret_cast<const float4*>(W2p + (size_t)h * kE);
                const float4 w1 = *reinterpret_cast<const float4*>(W2p + (size_t)h * kE + 4);
                const float wb[8] = {w0.x, w0.y, w0.z, w0.w, w1.x, w1.y, w1.z, w1.w};
                #pragma unroll
                for (int j = 0; j < 8; ++j) {
                    lacc[0][j] = fmaf(gv.x, wb[j], lacc[0][j]);
                    lacc[1][j] = fmaf(gv.y, wb[j], lacc[1][j]);
                }
            }
        }
    }

    // --- write GEMM2 partial: exclusive slice (mode 0) or atomics (mode 1)
    if (atomicMode) {
        #pragma unroll
        for (int i = 0; i < 2; ++i)
            #pragma unroll
            for (int j = 0; j < 8; ++j)
                atomicAdd(dst + (size_t)(rowBase + g_r0 + i) * kE + g_e0 + j, lacc[i][j]);
    } else {
        float* drow = dst + ((size_t)hSplit * kN + rowBase + g_r0) * kE + g_e0;
        #pragma unroll
        for (int i = 0; i < 2; ++i) {
            *reinterpret_cast<float4*>(drow + (size_t)i * kE) =
                make_float4(lacc[i][0], lacc[i][1], lacc[i][2], lacc[i][3]);
            *reinterpret_cast<float4*>(drow + (size_t)i * kE + 4) =
                make_float4(lacc[i][4], lacc[i][5], lacc[i][6], lacc[i][7]);
        }
    }
}

// ---------------------------------------------------------------------------
// Fallback fp32 GEMM1 (verified R1 kernel) — used when ws is too small
// ---------------------------------------------------------------------------
__global__ __launch_bounds__(256, 2)
void gemm1_kernel(const float* __restrict__ x, const float* __restrict__ W1,
                  const float* __restrict__ b1, const float* __restrict__ W2,
                  float* __restrict__ logits)
{
    __shared__ __align__(16) float smem[64 * 132];
    float* As = smem;
    float* Bs = smem + 32 * 128;
    float* gS = smem;

    const int t  = threadIdx.x;
    const int bx = blockIdx.x;
    const int rowBlock = bx >> 2;
    const int hSplit   = bx & 3;
    const int rowBase  = rowBlock * 128;
    const int hBase0   = hSplit * 1024;

    const int ty = t >> 4;
    const int tx = t & 15;
    const int r0 = ty * 8;
    const int c0 = tx * 8;
    const int g_r0 = (t >> 3) * 4;
    const int g_e0 = (t & 7) * 8;

    float lacc[4][8];
    #pragma unroll
    for (int i = 0; i < 4; ++i)
        #pragma unroll
        for (int j = 0; j < 8; ++j) lacc[i][j] = 0.0f;

    for (int chunk = 0; chunk < 8; ++chunk) {
        const int hBase = hBase0 + chunk * 128;
        float C[8][8];
        #pragma unroll
        for (int i = 0; i < 8; ++i)
            #pragma unroll
            for (int j = 0; j < 8; ++j) C[i][j] = 0.0f;

        for (int kt = 0; kt < kD; kt += 32) {
            __syncthreads();
            #pragma unroll
            for (int i = 0; i < 4; ++i) {
                const int f  = t + 256 * i;
                const int m  = f >> 3;
                const int kq = (f & 7) * 4;
                const float4 v = *reinterpret_cast<const float4*>(
                    x + (size_t)(rowBase + m) * kD + kt + kq);
                As[(kq + 0) * 128 + m] = v.x;
                As[(kq + 1) * 128 + m] = v.y;
                As[(kq + 2) * 128 + m] = v.z;
                As[(kq + 3) * 128 + m] = v.w;
            }
            #pragma unroll
            for (int i = 0; i < 4; ++i) {
                const int f  = t + 256 * i;
                const int k  = f >> 5;
                const int n4 = (f & 31) * 4;
                *reinterpret_cast<float4*>(Bs + k * 128 + n4) =
                    *reinterpret_cast<const float4*>(W1 + (size_t)(kt + k) * kH + hBase + n4);
            }
            __syncthreads();
            #pragma unroll 8
            for (int k = 0; k < 32; ++k) {
                const float4 a0 = *reinterpret_cast<const float4*>(As + k * 128 + r0);
                const float4 a1 = *reinterpret_cast<const float4*>(As + k * 128 + r0 + 4);
                const float4 b0 = *reinterpret_cast<const float4*>(Bs + k * 128 + c0);
                const float4 b1v = *reinterpret_cast<const float4*>(Bs + k * 128 + c0 + 4);
                const float a[8] = {a0.x, a0.y, a0.z, a0.w, a1.x, a1.y, a1.z, a1.w};
                const float b[8] = {b0.x, b0.y, b0.z, b0.w, b1v.x, b1v.y, b1v.z, b1v.w};
                #pragma unroll
                for (int i = 0; i < 8; ++i)
                    #pragma unroll
                    for (int j = 0; j < 8; ++j)
                        C[i][j] = fmaf(a[i], b[j], C[i][j]);
            }
        }

        #pragma unroll
        for (int j = 0; j < 8; ++j) {
            const float bb = b1[hBase + c0 + j];
            #pragma unroll
            for (int i = 0; i < 8; ++i) {
                const float hv = C[i][j] + bb;
                C[i][j] = 0.5f * hv * (1.0f + erff(hv * 0.70710678118654752f));
            }
        }

        for (int half = 0; half < 2; ++half) {
            __syncthreads();
            if ((tx >> 3) == half) {
                const int hloc0 = c0 - half * 64;
                #pragma unroll
                for (int j = 0; j < 8; ++j) {
                    const float4 col = make_float4(C[0][j], C[1][j], C[2][j], C[3][j]);
                    const float4 col2 = make_float4(C[4][j], C[5][j], C[6][j], C[7][j]);
                    *reinterpret_cast<float4*>(gS + (hloc0 + j) * 132 + r0)     = col;
                    *reinterpret_cast<float4*>(gS + (hloc0 + j) * 132 + r0 + 4) = col2;
                }
            }
            __syncthreads();
            const float* W2p = W2 + (size_t)(hBase + half * 64) * kE + g_e0;
            #pragma unroll 4
            for (int h = 0; h < 64; ++h) {
                const float4 gv = *reinterpret_cast<const float4*>(gS + h * 132 + g_r0);
                const float4 w0 = *reinterpret_cast<const float4*>(W2p + (size_t)h * kE);
                const float4 w1 = *reinterpret_cast<const float4*>(W2p + (size_t)h * kE + 4);
                const float ga[4] = {gv.x, gv.y, gv.z, gv.w};
                const float wb[8] = {w0.x, w0.y, w0.z, w0.w, w1.x, w1.y, w1.z, w1.w};
                #pragma unroll
                for (int i = 0; i < 4; ++i)
                    #pragma unroll
                    for (int j = 0; j < 8; ++j)
                        lacc[i][j] = fmaf(ga[i], wb[j], lacc[i][j]);
            }
        }
    }

    #pragma unroll
    for (int i = 0; i < 4; ++i)
        #pragma unroll
        for (int j = 0; j < 8; ++j)
            atomicAdd(logits + (size_t)(rowBase + g_r0 + i) * kE + g_e0 + j, lacc[i][j]);
}

// ---------------------------------------------------------------------------
// Router: logits from partials (mode 0) or logits buffer (mode 1); softmax,
// shared split, top-2 with min-index tie-break, indices written as float.
// ---------------------------------------------------------------------------
__global__ __launch_bounds__(256)
void router_kernel(const float* __restrict__ b2, const float* __restrict__ src,
                   int atomicMode, float* __restrict__ out)
{
    const int lane = threadIdx.x & 63;
    const int row  = blockIdx.x * 4 + (threadIdx.x >> 6);

    float logit;
    if (atomicMode) {
        logit = src[(size_t)row * kE + lane] + b2[lane];
    } else {
        const float* p = src + (size_t)row * kE + lane;
        logit = p[0] + p[(size_t)kN * kE] + p[(size_t)2 * kN * kE] +
                p[(size_t)3 * kN * kE] + b2[lane];
    }

    float m = logit;
    #pragma unroll
    for (int off = 32; off > 0; off >>= 1) m = fmaxf(m, __shfl_xor(m, off));
    const float p = expf(logit - m);
    float s = p;
    #pragma unroll
    for (int off = 32; off > 0; off >>= 1) s += __shfl_xor(s, off);
    const float w = p / s;

    out[OFF_W + (size_t)row * kE + lane] = w;
    if (lane < kShared) out[OFF_GW + (size_t)row * kShared + lane] = w;

    float v1 = (lane >= kShared) ? w : -1.0f;
    int   i1 = lane - kShared;
    #pragma unroll
    for (int off = 32; off > 0; off >>= 1) {
        const float ov = __shfl_xor(v1, off);
        const int   oi = __shfl_xor(i1, off);
        if (ov > v1 || (ov == v1 && oi < i1)) { v1 = ov; i1 = oi; }
    }
    float v2 = (lane >= kShared && (lane - kShared) != i1) ? w : -1.0f;
    int   i2 = lane - kShared;
    #pragma unroll
    for (int off = 32; off > 0; off >>= 1) {
        const float ov = __shfl_xor(v2, off);
        const int   oi = __shfl_xor(i2, off);
        if (ov > v2 || (ov == v2 && oi < i2)) { v2 = ov; i2 = oi; }
    }
    if (lane == 0) {
        out[OFF_LW + (size_t)row * 2 + 0] = v1;
        out[OFF_LW + (size_t)row * 2 + 1] = v2;
        out[OFF_LI + (size_t)row * 2 + 0] = (float)i1;
        out[OFF_LI + (size_t)row * 2 + 1] = (float)i2;
    }
}

extern "C" void kernel_launch(void* const* d_in, const int* in_sizes, int n_in,
                              void* d_out, int out_size, void* d_ws, size_t ws_size,
                              hipStream_t stream)
{
    const float* x  = (const float*)d_in[0];
    const float* W1 = (const float*)d_in[1];
    const float* b1 = (const float*)d_in[2];
    const float* W2 = (const float*)d_in[3];
    const float* b2 = (const float*)d_in[4];
    float* out = (float*)d_out;
    float* logits = out + OFF_W;

    if (ws_size >= WS_BASE) {
        _Float16* base = (_Float16*)d_ws;
        const int atomicMode = (ws_size >= WS_FULL) ? 0 : 1;
        float* dst = atomicMode ? logits : ((float*)d_ws + PART_FLOAT_OFF);
        if (atomicMode)
            hipMemsetAsync(logits, 0, (size_t)kN * kE * sizeof(float), stream);
        hipLaunchKernelGGL(convert_x, dim3(kN * kD / 1024), dim3(256), 0, stream,
                           x, base + XH_OFF, base + XL_OFF);
        hipLaunchKernelGGL(convert_w1t, dim3((kD / 64) * (kH / 64)), dim3(256), 0, stream,
                           W1, base + W1TH_OFF, base + W1TL_OFF);
        hipLaunchKernelGGL(gemm1_mfma, dim3((kN / 64) * HSPLIT), dim3(256), 0, stream,
                           base + XH_OFF, b1, W2, dst, atomicMode);
        hipLaunchKernelGGL(router_kernel, dim3(kN / 4), dim3(256), 0, stream,
                           b2, dst, atomicMode, out);
    } else {
        hipMemsetAsync(logits, 0, (size_t)kN * kE * sizeof(float), stream);
        hipLaunchKernelGGL(gemm1_kernel, dim3((kN / 128) * 4), dim3(256), 0, stream,
                           x, W1, b1, W2, logits);
        hipLaunchKernelGGL(router_kernel, dim3(kN / 4), dim3(256), 0, stream,
                           b2, logits, 1, out);
    }
}